// Round 23
// baseline (104.574 us; speedup 1.0000x reference)
//
#include <hip/hip_runtime.h>
#include <hip/hip_bf16.h>
#include <float.h>
#include <math.h>

// Problem constants: B=2, L=2048, D=1024, NH=16, HD=64
#define BB  2
#define LLEN 2048
#define DD  1024
#define NHH 16
#define HDD 64
#define MROWS (BB * LLEN)   // 4096

typedef __bf16 bf16x8  __attribute__((ext_vector_type(8)));
typedef float  f32x4   __attribute__((ext_vector_type(4)));
typedef float  f32x16  __attribute__((ext_vector_type(16)));
typedef ushort us8     __attribute__((ext_vector_type(8)));

#define EXP2F(x) __builtin_amdgcn_exp2f(x)   // 1-inst v_exp_f32

static __device__ __forceinline__ ushort f2bf(float f) {
    __hip_bfloat16 h = __float2bfloat16(f);
    return *reinterpret_cast<ushort*>(&h);
}
static __device__ __forceinline__ float bfu(ushort u) {
    unsigned x = (unsigned)u << 16;
    return __uint_as_float(x);
}
static __device__ __forceinline__ unsigned pack2(float a, float b) {
    return (unsigned)f2bf(a) | ((unsigned)f2bf(b) << 16);
}

__device__ __forceinline__ void gload16(const void* g, void* l) {
    __builtin_amdgcn_global_load_lds(
        (const __attribute__((address_space(1))) void*)g,
        (__attribute__((address_space(3))) void*)l, 16, 0, 0);
}

// ---------------------------------------------------------------------------
// Weight transposes+converts (z=0..3) + x fp32->bf16 (z=4) in ONE launch.
// ---------------------------------------------------------------------------
__global__ __launch_bounds__(256) void wt_cvt_all_k(const float* __restrict__ w0,
                                                    const float* __restrict__ w1,
                                                    const float* __restrict__ w2,
                                                    const float* __restrict__ w3,
                                                    const float* __restrict__ xin,
                                                    ushort* __restrict__ qkv,
                                                    ushort* __restrict__ wo,
                                                    ushort* __restrict__ xout) {
    const int z = blockIdx.z;
    const int tid = threadIdx.x;
    if (z == 4) {
        // x: 4M floats; 256 blocks x 256 thr x 16 float4
        const int bx = blockIdx.y * 16 + blockIdx.x;   // 0..255
        const float4* src = reinterpret_cast<const float4*>(xin);
        ushort4* dst = reinterpret_cast<ushort4*>(xout);
        const int base = bx * 4096 + tid;
#pragma unroll
        for (int it = 0; it < 16; ++it) {
            float4 v = src[base + it * 256];
            ushort4 o;
            o.x = f2bf(v.x); o.y = f2bf(v.y); o.z = f2bf(v.z); o.w = f2bf(v.w);
            dst[base + it * 256] = o;
        }
        return;
    }
    __shared__ float T[64][65];
    const float* in = (z == 0) ? w0 : (z == 1) ? w1 : (z == 2) ? w2 : w3;
    ushort* out = (z < 3) ? (qkv + (size_t)z * 1024 * DD) : wo;

    const int r0 = blockIdx.y * 64, c0 = blockIdx.x * 64;
    for (int i = tid; i < 64 * 16; i += 256) {
        int r = i >> 4, c4 = (i & 15) * 4;
        float4 v = *reinterpret_cast<const float4*>(&in[(size_t)(r0 + r) * DD + c0 + c4]);
        T[r][c4 + 0] = v.x; T[r][c4 + 1] = v.y; T[r][c4 + 2] = v.z; T[r][c4 + 3] = v.w;
    }
    __syncthreads();
    for (int i = tid; i < 64 * 16; i += 256) {
        int rr = i >> 4, cc4 = (i & 15) * 4;
        ushort4 o;
        o.x = f2bf(T[cc4 + 0][rr]);
        o.y = f2bf(T[cc4 + 1][rr]);
        o.z = f2bf(T[cc4 + 2][rr]);
        o.w = f2bf(T[cc4 + 3][rr]);
        *reinterpret_cast<ushort4*>(&out[(size_t)(c0 + rr) * DD + r0 + cc4]) = o;
    }
}

// ---------------------------------------------------------------------------
// bf16 MFMA GEMM: small tiles + DEPTH-2 PIPELINE (3 buffers, counted vmcnt):
// iter i: issue STAGE(i+2) -> compute buf(i) -> s_waitcnt vmcnt(LOADS)
// (buf(i+1) landed; buf(i+2) stays in flight) -> raw s_barrier.
// Loads get ~2 full iterations of cover (~500+ cy) vs depth-1's ~230.
//   MODE 1 (QKV): 64x128 tile, grid (24,64), LDS 72KB (2 blocks/CU), LOADS=6.
//   MODE 0 (out): 64x64 tile,  grid (16,64), LDS 48KB (3 blocks/CU), LOADS=4.
// Race audit: buffer written at iter i last read at iter i-1 (barrier-ordered);
// per-wave vmcnt precedes barrier -> all waves' i+1 writes visible after it.
// ---------------------------------------------------------------------------
template <int MODE>
__global__ __launch_bounds__(256, 2) void gemm_mfma_k(
    const __bf16* __restrict__ A, const __bf16* __restrict__ Bt,
    const float* __restrict__ bias0, const float* __restrict__ bias1,
    const float* __restrict__ bias2,
    float* __restrict__ out_f32,
    __hip_bfloat16* __restrict__ oq, __hip_bfloat16* __restrict__ ok,
    __hip_bfloat16* __restrict__ ov) {
    constexpr int K  = DD;
    constexpr int NF = (MODE == 1) ? 8 : 4;      // n-frags per wave
    constexpr int BN = NF * 16;                  // tile N: 128 or 64
    constexpr int HALF = (64 + BN) * 64;         // elems per buffer
    __shared__ char smem[3 * HALF * 2];          // 72KB or 48KB
    __bf16* smem_e = (__bf16*)smem;

    const int tid  = threadIdx.x;
    const int w    = tid >> 6;
    const int lane = tid & 63;
    const int lr   = lane & 15;
    const int lg   = lane >> 4;
    const int bm = blockIdx.y * 64, bn = blockIdx.x * BN;

    const int srow8 = lane >> 3;
    const int schk  = (lane & 7) ^ srow8;        // pre-swizzled src chunk
    const __bf16* gA = A  + (size_t)(bm + w * 16 + srow8) * K + schk * 8;
    const __bf16* gB = Bt + (size_t)(bn + w * (NF * 4) + srow8) * K + schk * 8;

    f32x4 acc[NF] = {};
    const int l7 = lr & 7;

    auto STAGE = [&](int buf, int k0) {
        __bf16* base = smem_e + buf * HALF;
        char* lA = (char*)base + w * 16 * 128;
        char* lB = (char*)(base + 4096) + w * (NF * 4) * 128;
#pragma unroll
        for (int c = 0; c < 2; ++c)
            gload16(gA + (size_t)(c * 8) * K + k0, lA + c * 1024);
#pragma unroll
        for (int c = 0; c < NF / 2; ++c)
            gload16(gB + (size_t)(c * 8) * K + k0, lB + c * 1024);
    };

    STAGE(0, 0);
    STAGE(1, 64);
    if constexpr (MODE == 1)
        asm volatile("s_waitcnt vmcnt(6)" ::: "memory");
    else
        asm volatile("s_waitcnt vmcnt(4)" ::: "memory");
    __builtin_amdgcn_s_barrier();

#pragma unroll 1
    for (int i = 0; i < 16; ++i) {
        if (i + 2 < 16) STAGE((i + 2) % 3, (i + 2) * 64);   // depth-2 prefetch
        const __bf16* As_ = smem_e + (i % 3) * HALF;
        const __bf16* Bs_ = As_ + 4096;
#pragma unroll
        for (int kk = 0; kk < 2; ++kk) {
            const int rchk = ((kk * 4 + lg) ^ l7) << 3;
            bf16x8 a = *reinterpret_cast<const bf16x8*>(As_ + (w * 16 + lr) * 64 + rchk);
#pragma unroll
            for (int n = 0; n < NF; ++n) {
                bf16x8 b = *reinterpret_cast<const bf16x8*>(Bs_ + (n * 16 + lr) * 64 + rchk);
                acc[n] = __builtin_amdgcn_mfma_f32_16x16x32_bf16(a, b, acc[n], 0, 0, 0);
            }
        }
        if (i + 2 < 16) {
            if constexpr (MODE == 1)
                asm volatile("s_waitcnt vmcnt(6)" ::: "memory");   // i+1 landed
            else
                asm volatile("s_waitcnt vmcnt(4)" ::: "memory");
        } else if (i + 1 < 16) {
            asm volatile("s_waitcnt vmcnt(0)" ::: "memory");       // drain tail
        }
        __builtin_amdgcn_s_barrier();
    }

    if (MODE == 1) {
        const int seg = bn >> 10;
        const int colbase = bn & 1023;
        const int h0 = colbase >> 6;
        const int b  = bm >> 11;
        const int bmL = bm & 2047;
        if (seg == 2) {
#pragma unroll
            for (int n = 0; n < NF; ++n) {
                const int h  = h0 + (n >> 2);
                const int hd = (n & 3) * 16 + lr;
                const float bv = bias2[colbase + n * 16 + lr];
                const int rowb = bm + w * 16 + lg * 4;
                const int l0 = rowb & 2047;
                ushort4 st;
                st.x = f2bf(acc[n][0] + bv);
                st.y = f2bf(acc[n][1] + bv);
                st.z = f2bf(acc[n][2] + bv);
                st.w = f2bf(acc[n][3] + bv);
                const int bh = b * NHH + h;
                const int t  = l0 >> 5;
                const int j  = ((hd >> 5) << 1) | ((l0 >> 4) & 1);
                const int ln = (hd & 31) + ((l0 >> 3) & 1) * 32;
                const int e0 = l0 & 7;
                size_t base = ((((size_t)bh * 64 + t) * 4 + j) * 64 + ln) * 8 + e0;
                *reinterpret_cast<ushort4*>(&ov[base]) = st;
            }
        } else {
            const float* biasp = (seg == 0) ? bias0 : bias1;
            const float osc = (seg == 0) ? 0.18033688011112042f : 1.0f;
            ushort* LP = (ushort*)smem + w * 2048;
#pragma unroll
            for (int hh = 0; hh < 2; ++hh) {
#pragma unroll
                for (int n2 = 0; n2 < 2; ++n2) {
                    const int nA = hh * 4 + n2, nB = nA + 2;
                    const int d  = n2 * 16 + lr;
                    const float tsd = exp2f((float)d * -0.4152410118609203f);
                    const float bv0 = biasp[colbase + hh * 64 + d];
                    const float bv1 = biasp[colbase + hh * 64 + d + 32];
                    const int c0  = d >> 4;
                    const int hi8 = (d >> 3) & 1;
#pragma unroll
                    for (int i = 0; i < 4; ++i) {
                        const int lw = lg * 4 + i;
                        const int l  = bmL + w * 16 + lw;
                        float s, c;
                        __sincosf((float)l * tsd, &s, &c);
                        const float x0 = acc[nA][i] + bv0;
                        const float x1 = acc[nB][i] + bv1;
                        const int lnL = lw + 16 * hi8;
                        LP[hh * 1024 + (c0 * 32 + lnL) * 8 + (d & 7)] =
                            f2bf((x0 * c - x1 * s) * osc);
                        LP[hh * 1024 + ((c0 + 2) * 32 + lnL) * 8 + (d & 7)] =
                            f2bf((x1 * c + x0 * s) * osc);
                    }
                }
            }
            __syncthreads();
            ushort* dstp = (ushort*)((seg == 0) ? oq : ok);
            const int t   = (bmL >> 5) + (w >> 1);
            const int r0w = (w & 1) * 16;
#pragma unroll
            for (int hh = 0; hh < 2; ++hh) {
                const int bh = b * NHH + h0 + hh;
#pragma unroll
                for (int it = 0; it < 2; ++it) {
                    const int f = it * 64 + lane;
                    const int c = f >> 5, lnL = f & 31;
                    const int ln = r0w + (lnL & 15) + 32 * (lnL >> 4);
                    us8 v = *reinterpret_cast<const us8*>(&LP[hh * 1024 + f * 8]);
                    size_t base = ((((size_t)bh * 64 + t) * 4 + c) * 64 + ln) * 8;
                    *reinterpret_cast<us8*>(&dstp[base]) = v;
                }
            }
        }
    } else {
        float* FP = (float*)smem + w * 1024;
        __syncthreads();
#pragma unroll
        for (int n = 0; n < NF; ++n) {
            const int col = n * 16 + lr;
            const float bv = bias0[bn + col];
#pragma unroll
            for (int i = 0; i < 4; ++i)
                FP[(lg * 4 + i) * 64 + col] = acc[n][i] + bv;
        }
        __syncthreads();
#pragma unroll
        for (int it = 0; it < 4; ++it) {
            const int f = it * 64 + lane;
            const int row16 = f >> 4, cq = f & 15;
            float4 v = *reinterpret_cast<const float4*>(&FP[row16 * 64 + cq * 4]);
            const int row = bm + w * 16 + row16;
            *reinterpret_cast<float4*>(&out_f32[(size_t)row * DD + bn + cq * 4]) = v;
        }
    }
}

// ---------------------------------------------------------------------------
// Flash attention (causal), swapped-operand 32x32 MFMA, packed Q/K/V,
// no-max softmax, bf16 LDS partials. 2048 blocks = one qtile per block,
// heavy-first per XCD (LPT). (round-21/22, passing)
// ---------------------------------------------------------------------------
#define ATTN_LOAD(KF, VF, T0)                                                   \
    do {                                                                        \
        const __bf16* kp_ = kbase + (size_t)(T0) * 2048;                        \
        KF[0] = *reinterpret_cast<const bf16x8*>(kp_);                          \
        KF[1] = *reinterpret_cast<const bf16x8*>(kp_ + 512);                    \
        KF[2] = *reinterpret_cast<const bf16x8*>(kp_ + 1024);                   \
        KF[3] = *reinterpret_cast<const bf16x8*>(kp_ + 1536);                   \
        const __bf16* vp_ = vbase + (size_t)(T0) * 2048;                        \
        VF[0] = *reinterpret_cast<const bf16x8*>(vp_);                          \
        VF[1] = *reinterpret_cast<const bf16x8*>(vp_ + 512);                    \
        VF[2] = *reinterpret_cast<const bf16x8*>(vp_ + 1024);                   \
        VF[3] = *reinterpret_cast<const bf16x8*>(vp_ + 1536);                   \
    } while (0)

#define ATTN_TILE(KF, VF, T0, MASKIT, QG)                                       \
    do {                                                                        \
        f32x16 s_ = {};                                                         \
        __builtin_amdgcn_s_setprio(1);                                          \
        s_ = __builtin_amdgcn_mfma_f32_32x32x16_bf16(KF[0], qf[0], s_, 0, 0, 0);\
        s_ = __builtin_amdgcn_mfma_f32_32x32x16_bf16(KF[1], qf[1], s_, 0, 0, 0);\
        s_ = __builtin_amdgcn_mfma_f32_32x32x16_bf16(KF[2], qf[2], s_, 0, 0, 0);\
        s_ = __builtin_amdgcn_mfma_f32_32x32x16_bf16(KF[3], qf[3], s_, 0, 0, 0);\
        __builtin_amdgcn_s_setprio(0);                                          \
        float p_[16];                                                           \
        const int k0_ = (T0) * 32;                                              \
        if (MASKIT) {                                                           \
            _Pragma("unroll")                                                   \
            for (int i = 0; i < 16; ++i) {                                      \
                int kkg_ = k0_ + (i & 3) + 8 * (i >> 2) + 4 * hi;               \
                p_[i] = (kkg_ <= (QG)) ? EXP2F(s_[i]) : 0.f;                    \
            }                                                                   \
        } else {                                                                \
            _Pragma("unroll")                                                   \
            for (int i = 0; i < 16; ++i) p_[i] = EXP2F(s_[i]);                  \
        }                                                                       \
        _Pragma("unroll")                                                       \
        for (int i = 0; i < 16; ++i) lsum += p_[i];                             \
        unsigned u_[8], x_[8];                                                  \
        _Pragma("unroll")                                                       \
        for (int j = 0; j < 8; ++j)                                             \
            u_[j] = pack2(p_[2 * j], p_[2 * j + 1]);                            \
        _Pragma("unroll")                                                       \
        for (int j = 0; j < 8; ++j)                                             \
            x_[j] = (unsigned)__shfl_xor((int)u_[j], 32);                       \
        union { unsigned d[4]; bf16x8 v; } B1_, B2_;                            \
        if (hi == 0) {                                                          \
            B1_.d[0] = u_[0]; B1_.d[1] = u_[1]; B1_.d[2] = x_[0]; B1_.d[3] = x_[1]; \
            B2_.d[0] = u_[4]; B2_.d[1] = u_[5]; B2_.d[2] = x_[4]; B2_.d[3] = x_[5]; \
        } else {                                                                \
            B1_.d[0] = x_[2]; B1_.d[1] = x_[3]; B1_.d[2] = u_[2]; B1_.d[3] = u_[3]; \
            B2_.d[0] = x_[6]; B2_.d[1] = x_[7]; B2_.d[2] = u_[6]; B2_.d[3] = u_[7]; \
        }                                                                       \
        __builtin_amdgcn_s_setprio(1);                                          \
        o0 = __builtin_amdgcn_mfma_f32_32x32x16_bf16(VF[0], B1_.v, o0, 0, 0, 0);\
        o0 = __builtin_amdgcn_mfma_f32_32x32x16_bf16(VF[1], B2_.v, o0, 0, 0, 0);\
        o1 = __builtin_amdgcn_mfma_f32_32x32x16_bf16(VF[2], B1_.v, o1, 0, 0, 0);\
        o1 = __builtin_amdgcn_mfma_f32_32x32x16_bf16(VF[3], B2_.v, o1, 0, 0, 0);\
        __builtin_amdgcn_s_setprio(0);                                          \
    } while (0)

__global__ __launch_bounds__(256) void attn_mfma17_k(const __bf16* __restrict__ Qp,
                                                     const __bf16* __restrict__ Kp,
                                                     const __bf16* __restrict__ Vp,
                                                     __hip_bfloat16* __restrict__ ctx) {
    __shared__ ushort oLs[4][64][34];
    __shared__ float lvL[4][64];

    const int tid  = threadIdx.x;
    const int w    = tid >> 6;
    const int lane = tid & 63;
    const int q32  = lane & 31;
    const int hi   = lane >> 5;

    const int bid = blockIdx.x;
    const int g_  = (bid & 7) * 256 + (bid >> 3);
    const int bh  = g_ >> 6;
    const int qt  = 63 - (g_ & 63);
    const int qg  = qt * 32 + q32;

    const __bf16* qbase = Qp + (size_t)bh * (64 * 4 * 512) + lane * 8;
    const __bf16* kbase = Kp + (size_t)bh * (64 * 4 * 512) + lane * 8;
    const __bf16* vbase = Vp + (size_t)bh * (64 * 4 * 512) + lane * 8;

    const int b = bh >> 4, h = bh & 15;

    bf16x8 qf[4];
    const __bf16* qp_ = qbase + (size_t)qt * 2048;
    qf[0] = *reinterpret_cast<const bf16x8*>(qp_);
    qf[1] = *reinterpret_cast<const bf16x8*>(qp_ + 512);
    qf[2] = *reinterpret_cast<const bf16x8*>(qp_ + 1024);
    qf[3] = *reinterpret_cast<const bf16x8*>(qp_ + 1536);

    f32x16 o0 = {}, o1 = {};
    float lsum = 0.f;

    bf16x8 kf[4], vf[4];
    for (int t = w; t <= qt; t += 4) {
        ATTN_LOAD(kf, vf, t);
        ATTN_TILE(kf, vf, t, t == qt, qg);
    }

#pragma unroll
    for (int r = 0; r < 16; r += 2) {
        *reinterpret_cast<unsigned*>(&oLs[w][lane][r])      = pack2(o0[r], o0[r + 1]);
        *reinterpret_cast<unsigned*>(&oLs[w][lane][16 + r]) = pack2(o1[r], o1[r + 1]);
    }
    lvL[w][lane] = lsum;
    __syncthreads();

    float Lt = 0.f;
#pragma unroll
    for (int j = 0; j < 4; ++j)
        Lt += lvL[j][q32] + lvL[j][q32 + 32];
    const float inv = 1.0f / Lt;

    __hip_bfloat16* dst = ctx + ((size_t)(b * LLEN + qg)) * DD + h * HDD;
    const int T = w >> 1;
    const int gb = (w & 1) * 2;
#pragma unroll
    for (int g2 = 0; g2 < 2; ++g2) {
        const int g = gb + g2;
        const int rb = T * 16 + 4 * g;
        float acc4[4] = {0.f, 0.f, 0.f, 0.f};
#pragma unroll
        for (int j = 0; j < 4; ++j) {
            unsigned a = *reinterpret_cast<const unsigned*>(&oLs[j][lane][rb]);
            unsigned c = *reinterpret_cast<const unsigned*>(&oLs[j][lane][rb + 2]);
            acc4[0] += bfu((ushort)(a & 0xffff));
            acc4[1] += bfu((ushort)(a >> 16));
            acc4[2] += bfu((ushort)(c & 0xffff));
            acc4[3] += bfu((ushort)(c >> 16));
        }
        ushort st4[4];
#pragma unroll
        for (int e = 0; e < 4; ++e) st4[e] = f2bf(acc4[e] * inv);
        const int d = T * 32 + 8 * g + 4 * hi;
        *reinterpret_cast<ushort4*>(dst + d) = *reinterpret_cast<ushort4*>(st4);
    }
}

// ---------------------------------------------------------------------------
extern "C" void kernel_launch(void* const* d_in, const int* in_sizes, int n_in,
                              void* d_out, int out_size, void* d_ws, size_t ws_size,
                              hipStream_t stream) {
    const float* x    = (const float*)d_in[0];
    const float* wq_w = (const float*)d_in[1];
    const float* wq_b = (const float*)d_in[2];
    const float* wk_w = (const float*)d_in[3];
    const float* wk_b = (const float*)d_in[4];
    const float* wv_w = (const float*)d_in[5];
    const float* wv_b = (const float*)d_in[6];
    const float* wo_w = (const float*)d_in[7];
    const float* wo_b = (const float*)d_in[8];
    float* out = (float*)d_out;

    const size_t MB = 1024 * 1024;
    char* p = (char*)d_ws;
    __bf16* x16   = (__bf16*)p;            p += 8 * MB;   // [4096][1024]
    __bf16* wqkvt = (__bf16*)p;            p += 6 * MB;   // [3072][1024]
    __bf16* wot   = (__bf16*)p;            p += 2 * MB;   // [1024][1024]
    __hip_bfloat16* qp16 = (__hip_bfloat16*)p; p += 8 * MB;  // packed QP (SC2-scaled)
    __hip_bfloat16* kp16 = (__hip_bfloat16*)p; p += 8 * MB;  // packed KP
    __hip_bfloat16* vp16 = (__hip_bfloat16*)p; p += 8 * MB;  // packed VP
    __hip_bfloat16* ctx16 = (__hip_bfloat16*)p;               // [B][L][D]

    // weight transposes + x conversion (one launch, z=0..4)
    hipLaunchKernelGGL(wt_cvt_all_k, dim3(16, 16, 5), dim3(256), 0, stream,
                       wq_w, wk_w, wv_w, wo_w, x,
                       (ushort*)wqkvt, (ushort*)wot, (ushort*)x16);

    // fused QKV projection + RoPE + Q scale fold + Q/K/V fragment packing
    hipLaunchKernelGGL((gemm_mfma_k<1>), dim3(24, 64), dim3(256), 0, stream,
                       x16, wqkvt, wq_b, wk_b, wv_b, (float*)nullptr, qp16, kp16, vp16);

    // attention (single qtile/block, 2048 blocks, heavy-first, split-KV)
    hipLaunchKernelGGL(attn_mfma17_k, dim3(2048), dim3(256), 0, stream,
                       (const __bf16*)qp16, (const __bf16*)kp16, (const __bf16*)vp16, ctx16);

    // output projection (64x64 tiles, depth-2 pipeline)
    hipLaunchKernelGGL((gemm_mfma_k<0>), dim3(16, 64), dim3(256), 0, stream,
                       (const __bf16*)ctx16, wot, wo_b, (const float*)nullptr, (const float*)nullptr,
                       out, (__hip_bfloat16*)nullptr, (__hip_bfloat16*)nullptr, (__hip_bfloat16*)nullptr);
}

// Round 24
// 101.113 us; speedup vs baseline: 1.0342x; 1.0342x over previous
//
#include <hip/hip_runtime.h>
#include <hip/hip_bf16.h>
#include <float.h>
#include <math.h>

// Problem constants: B=2, L=2048, D=1024, NH=16, HD=64
#define BB  2
#define LLEN 2048
#define DD  1024
#define NHH 16
#define HDD 64
#define MROWS (BB * LLEN)   // 4096

typedef __bf16 bf16x8  __attribute__((ext_vector_type(8)));
typedef float  f32x4   __attribute__((ext_vector_type(4)));
typedef float  f32x16  __attribute__((ext_vector_type(16)));
typedef ushort us8     __attribute__((ext_vector_type(8)));

#define EXP2F(x) __builtin_amdgcn_exp2f(x)   // 1-inst v_exp_f32

static __device__ __forceinline__ ushort f2bf(float f) {
    __hip_bfloat16 h = __float2bfloat16(f);
    return *reinterpret_cast<ushort*>(&h);
}
static __device__ __forceinline__ float bfu(ushort u) {
    unsigned x = (unsigned)u << 16;
    return __uint_as_float(x);
}
static __device__ __forceinline__ unsigned pack2(float a, float b) {
    return (unsigned)f2bf(a) | ((unsigned)f2bf(b) << 16);
}

__device__ __forceinline__ void gload16(const void* g, void* l) {
    __builtin_amdgcn_global_load_lds(
        (const __attribute__((address_space(1))) void*)g,
        (__attribute__((address_space(3))) void*)l, 16, 0, 0);
}

// ---------------------------------------------------------------------------
// x fp32 -> bf16, 4 elems/thread
// ---------------------------------------------------------------------------
__global__ __launch_bounds__(256) void cvt_x_k(const float* __restrict__ in,
                                               ushort* __restrict__ out) {
    int idx = blockIdx.x * 256 + threadIdx.x;
    float4 v = reinterpret_cast<const float4*>(in)[idx];
    ushort4 o;
    o.x = f2bf(v.x); o.y = f2bf(v.y); o.z = f2bf(v.z); o.w = f2bf(v.w);
    reinterpret_cast<ushort4*>(out)[idx] = o;
}

// ---------------------------------------------------------------------------
// All 4 weight transposes+converts in one launch: fp32 [1024][1024] -> bf16 [N][K]
// ---------------------------------------------------------------------------
__global__ __launch_bounds__(256) void wt_cvt_all_k(const float* __restrict__ w0,
                                                    const float* __restrict__ w1,
                                                    const float* __restrict__ w2,
                                                    const float* __restrict__ w3,
                                                    ushort* __restrict__ qkv,
                                                    ushort* __restrict__ wo) {
    __shared__ float T[64][65];
    const int z = blockIdx.z;
    const float* in = (z == 0) ? w0 : (z == 1) ? w1 : (z == 2) ? w2 : w3;
    ushort* out = (z < 3) ? (qkv + (size_t)z * 1024 * DD) : wo;

    const int r0 = blockIdx.y * 64, c0 = blockIdx.x * 64;
    const int tid = threadIdx.x;
    for (int i = tid; i < 64 * 16; i += 256) {
        int r = i >> 4, c4 = (i & 15) * 4;
        float4 v = *reinterpret_cast<const float4*>(&in[(size_t)(r0 + r) * DD + c0 + c4]);
        T[r][c4 + 0] = v.x; T[r][c4 + 1] = v.y; T[r][c4 + 2] = v.z; T[r][c4 + 3] = v.w;
    }
    __syncthreads();
    for (int i = tid; i < 64 * 16; i += 256) {
        int rr = i >> 4, cc4 = (i & 15) * 4;
        ushort4 o;
        o.x = f2bf(T[cc4 + 0][rr]);
        o.y = f2bf(T[cc4 + 1][rr]);
        o.z = f2bf(T[cc4 + 2][rr]);
        o.w = f2bf(T[cc4 + 3][rr]);
        *reinterpret_cast<ushort4*>(&out[(size_t)(c0 + rr) * DD + r0 + cc4]) = o;
    }
}

// ---------------------------------------------------------------------------
// bf16 MFMA GEMM: small tiles + 2-PHASE DOUBLE BUFFER (round-22, best).
//   MODE 1 (QKV): 64x128 tile, grid (24,64), LDS 48KB (3 blocks/CU).
//   MODE 0 (out): 64x64 tile,  grid (16,64), LDS 32KB (4 blocks/CU).
// ---------------------------------------------------------------------------
template <int MODE>
__global__ __launch_bounds__(256, 3) void gemm_mfma_k(
    const __bf16* __restrict__ A, const __bf16* __restrict__ Bt,
    const float* __restrict__ bias0, const float* __restrict__ bias1,
    const float* __restrict__ bias2,
    float* __restrict__ out_f32,
    __hip_bfloat16* __restrict__ oq, __hip_bfloat16* __restrict__ ok,
    __hip_bfloat16* __restrict__ ov) {
    constexpr int K  = DD;
    constexpr int NF = (MODE == 1) ? 8 : 4;      // n-frags per wave
    constexpr int BN = NF * 16;                  // tile N: 128 or 64
    constexpr int HALF = (64 + BN) * 64;         // elems per buffer
    __shared__ char smem[2 * HALF * 2];          // 48KB or 32KB
    __bf16* smem_e = (__bf16*)smem;

    const int tid  = threadIdx.x;
    const int w    = tid >> 6;
    const int lane = tid & 63;
    const int lr   = lane & 15;
    const int lg   = lane >> 4;
    const int bm = blockIdx.y * 64, bn = blockIdx.x * BN;

    const int srow8 = lane >> 3;
    const int schk  = (lane & 7) ^ srow8;        // pre-swizzled src chunk
    const __bf16* gA = A  + (size_t)(bm + w * 16 + srow8) * K + schk * 8;
    const __bf16* gB = Bt + (size_t)(bn + w * (NF * 4) + srow8) * K + schk * 8;

    f32x4 acc[NF] = {};
    const int l7 = lr & 7;

    auto STAGE = [&](int buf, int k0) {
        __bf16* base = smem_e + buf * HALF;
        char* lA = (char*)base + w * 16 * 128;
        char* lB = (char*)(base + 4096) + w * (NF * 4) * 128;
#pragma unroll
        for (int c = 0; c < 2; ++c)
            gload16(gA + (size_t)(c * 8) * K + k0, lA + c * 1024);
#pragma unroll
        for (int c = 0; c < NF / 2; ++c)
            gload16(gB + (size_t)(c * 8) * K + k0, lB + c * 1024);
    };

    STAGE(0, 0);
    __syncthreads();
    for (int i = 0; i < 16; ++i) {
        if (i < 15) STAGE((i + 1) & 1, (i + 1) * 64);   // issue-early prefetch
        const __bf16* As_ = smem_e + (i & 1) * HALF;
        const __bf16* Bs_ = As_ + 4096;
#pragma unroll
        for (int kk = 0; kk < 2; ++kk) {
            const int rchk = ((kk * 4 + lg) ^ l7) << 3;
            bf16x8 a = *reinterpret_cast<const bf16x8*>(As_ + (w * 16 + lr) * 64 + rchk);
#pragma unroll
            for (int n = 0; n < NF; ++n) {
                bf16x8 b = *reinterpret_cast<const bf16x8*>(Bs_ + (n * 16 + lr) * 64 + rchk);
                acc[n] = __builtin_amdgcn_mfma_f32_16x16x32_bf16(a, b, acc[n], 0, 0, 0);
            }
        }
        __syncthreads();   // drains prefetch (had full compute phase) + buffer reuse
    }

    if (MODE == 1) {
        const int seg = bn >> 10;
        const int colbase = bn & 1023;
        const int h0 = colbase >> 6;
        const int b  = bm >> 11;
        const int bmL = bm & 2047;
        if (seg == 2) {
#pragma unroll
            for (int n = 0; n < NF; ++n) {
                const int h  = h0 + (n >> 2);
                const int hd = (n & 3) * 16 + lr;
                const float bv = bias2[colbase + n * 16 + lr];
                const int rowb = bm + w * 16 + lg * 4;
                const int l0 = rowb & 2047;
                ushort4 st;
                st.x = f2bf(acc[n][0] + bv);
                st.y = f2bf(acc[n][1] + bv);
                st.z = f2bf(acc[n][2] + bv);
                st.w = f2bf(acc[n][3] + bv);
                const int bh = b * NHH + h;
                const int t  = l0 >> 5;
                const int j  = ((hd >> 5) << 1) | ((l0 >> 4) & 1);
                const int ln = (hd & 31) + ((l0 >> 3) & 1) * 32;
                const int e0 = l0 & 7;
                size_t base = ((((size_t)bh * 64 + t) * 4 + j) * 64 + ln) * 8 + e0;
                *reinterpret_cast<ushort4*>(&ov[base]) = st;
            }
        } else {
            const float* biasp = (seg == 0) ? bias0 : bias1;
            const float osc = (seg == 0) ? 0.18033688011112042f : 1.0f;
            ushort* LP = (ushort*)smem + w * 2048;
#pragma unroll
            for (int hh = 0; hh < 2; ++hh) {
#pragma unroll
                for (int n2 = 0; n2 < 2; ++n2) {
                    const int nA = hh * 4 + n2, nB = nA + 2;
                    const int d  = n2 * 16 + lr;
                    const float tsd = exp2f((float)d * -0.4152410118609203f);
                    const float bv0 = biasp[colbase + hh * 64 + d];
                    const float bv1 = biasp[colbase + hh * 64 + d + 32];
                    const int c0  = d >> 4;
                    const int hi8 = (d >> 3) & 1;
#pragma unroll
                    for (int i = 0; i < 4; ++i) {
                        const int lw = lg * 4 + i;
                        const int l  = bmL + w * 16 + lw;
                        float s, c;
                        __sincosf((float)l * tsd, &s, &c);
                        const float x0 = acc[nA][i] + bv0;
                        const float x1 = acc[nB][i] + bv1;
                        const int lnL = lw + 16 * hi8;
                        LP[hh * 1024 + (c0 * 32 + lnL) * 8 + (d & 7)] =
                            f2bf((x0 * c - x1 * s) * osc);
                        LP[hh * 1024 + ((c0 + 2) * 32 + lnL) * 8 + (d & 7)] =
                            f2bf((x1 * c + x0 * s) * osc);
                    }
                }
            }
            __syncthreads();
            ushort* dstp = (ushort*)((seg == 0) ? oq : ok);
            const int t   = (bmL >> 5) + (w >> 1);
            const int r0w = (w & 1) * 16;
#pragma unroll
            for (int hh = 0; hh < 2; ++hh) {
                const int bh = b * NHH + h0 + hh;
#pragma unroll
                for (int it = 0; it < 2; ++it) {
                    const int f = it * 64 + lane;
                    const int c = f >> 5, lnL = f & 31;
                    const int ln = r0w + (lnL & 15) + 32 * (lnL >> 4);
                    us8 v = *reinterpret_cast<const us8*>(&LP[hh * 1024 + f * 8]);
                    size_t base = ((((size_t)bh * 64 + t) * 4 + c) * 64 + ln) * 8;
                    *reinterpret_cast<us8*>(&dstp[base]) = v;
                }
            }
        }
    } else {
        float* FP = (float*)smem + w * 1024;
        __syncthreads();
#pragma unroll
        for (int n = 0; n < NF; ++n) {
            const int col = n * 16 + lr;
            const float bv = bias0[bn + col];
#pragma unroll
            for (int i = 0; i < 4; ++i)
                FP[(lg * 4 + i) * 64 + col] = acc[n][i] + bv;
        }
        __syncthreads();
#pragma unroll
        for (int it = 0; it < 4; ++it) {
            const int f = it * 64 + lane;
            const int row16 = f >> 4, cq = f & 15;
            float4 v = *reinterpret_cast<const float4*>(&FP[row16 * 64 + cq * 4]);
            const int row = bm + w * 16 + row16;
            *reinterpret_cast<float4*>(&out_f32[(size_t)row * DD + bn + cq * 4]) = v;
        }
    }
}

// ---------------------------------------------------------------------------
// Flash attention (causal), swapped-operand 32x32 MFMA, packed Q/K/V,
// no-max softmax, bf16 LDS partials. 2048 blocks = one qtile per block,
// heavy-first per XCD (LPT). (round-21/22, passing)
// ---------------------------------------------------------------------------
#define ATTN_LOAD(KF, VF, T0)                                                   \
    do {                                                                        \
        const __bf16* kp_ = kbase + (size_t)(T0) * 2048;                        \
        KF[0] = *reinterpret_cast<const bf16x8*>(kp_);                          \
        KF[1] = *reinterpret_cast<const bf16x8*>(kp_ + 512);                    \
        KF[2] = *reinterpret_cast<const bf16x8*>(kp_ + 1024);                   \
        KF[3] = *reinterpret_cast<const bf16x8*>(kp_ + 1536);                   \
        const __bf16* vp_ = vbase + (size_t)(T0) * 2048;                        \
        VF[0] = *reinterpret_cast<const bf16x8*>(vp_);                          \
        VF[1] = *reinterpret_cast<const bf16x8*>(vp_ + 512);                    \
        VF[2] = *reinterpret_cast<const bf16x8*>(vp_ + 1024);                   \
        VF[3] = *reinterpret_cast<const bf16x8*>(vp_ + 1536);                   \
    } while (0)

#define ATTN_TILE(KF, VF, T0, MASKIT, QG)                                       \
    do {                                                                        \
        f32x16 s_ = {};                                                         \
        __builtin_amdgcn_s_setprio(1);                                          \
        s_ = __builtin_amdgcn_mfma_f32_32x32x16_bf16(KF[0], qf[0], s_, 0, 0, 0);\
        s_ = __builtin_amdgcn_mfma_f32_32x32x16_bf16(KF[1], qf[1], s_, 0, 0, 0);\
        s_ = __builtin_amdgcn_mfma_f32_32x32x16_bf16(KF[2], qf[2], s_, 0, 0, 0);\
        s_ = __builtin_amdgcn_mfma_f32_32x32x16_bf16(KF[3], qf[3], s_, 0, 0, 0);\
        __builtin_amdgcn_s_setprio(0);                                          \
        float p_[16];                                                           \
        const int k0_ = (T0) * 32;                                              \
        if (MASKIT) {                                                           \
            _Pragma("unroll")                                                   \
            for (int i = 0; i < 16; ++i) {                                      \
                int kkg_ = k0_ + (i & 3) + 8 * (i >> 2) + 4 * hi;               \
                p_[i] = (kkg_ <= (QG)) ? EXP2F(s_[i]) : 0.f;                    \
            }                                                                   \
        } else {                                                                \
            _Pragma("unroll")                                                   \
            for (int i = 0; i < 16; ++i) p_[i] = EXP2F(s_[i]);                  \
        }                                                                       \
        _Pragma("unroll")                                                       \
        for (int i = 0; i < 16; ++i) lsum += p_[i];                             \
        unsigned u_[8], x_[8];                                                  \
        _Pragma("unroll")                                                       \
        for (int j = 0; j < 8; ++j)                                             \
            u_[j] = pack2(p_[2 * j], p_[2 * j + 1]);                            \
        _Pragma("unroll")                                                       \
        for (int j = 0; j < 8; ++j)                                             \
            x_[j] = (unsigned)__shfl_xor((int)u_[j], 32);                       \
        union { unsigned d[4]; bf16x8 v; } B1_, B2_;                            \
        if (hi == 0) {                                                          \
            B1_.d[0] = u_[0]; B1_.d[1] = u_[1]; B1_.d[2] = x_[0]; B1_.d[3] = x_[1]; \
            B2_.d[0] = u_[4]; B2_.d[1] = u_[5]; B2_.d[2] = x_[4]; B2_.d[3] = x_[5]; \
        } else {                                                                \
            B1_.d[0] = x_[2]; B1_.d[1] = x_[3]; B1_.d[2] = u_[2]; B1_.d[3] = u_[3]; \
            B2_.d[0] = x_[6]; B2_.d[1] = x_[7]; B2_.d[2] = u_[6]; B2_.d[3] = u_[7]; \
        }                                                                       \
        __builtin_amdgcn_s_setprio(1);                                          \
        o0 = __builtin_amdgcn_mfma_f32_32x32x16_bf16(VF[0], B1_.v, o0, 0, 0, 0);\
        o0 = __builtin_amdgcn_mfma_f32_32x32x16_bf16(VF[1], B2_.v, o0, 0, 0, 0);\
        o1 = __builtin_amdgcn_mfma_f32_32x32x16_bf16(VF[2], B1_.v, o1, 0, 0, 0);\
        o1 = __builtin_amdgcn_mfma_f32_32x32x16_bf16(VF[3], B2_.v, o1, 0, 0, 0);\
        __builtin_amdgcn_s_setprio(0);                                          \
    } while (0)

__global__ __launch_bounds__(256) void attn_mfma17_k(const __bf16* __restrict__ Qp,
                                                     const __bf16* __restrict__ Kp,
                                                     const __bf16* __restrict__ Vp,
                                                     __hip_bfloat16* __restrict__ ctx) {
    __shared__ ushort oLs[4][64][34];
    __shared__ float lvL[4][64];

    const int tid  = threadIdx.x;
    const int w    = tid >> 6;
    const int lane = tid & 63;
    const int q32  = lane & 31;
    const int hi   = lane >> 5;

    const int bid = blockIdx.x;
    const int g_  = (bid & 7) * 256 + (bid >> 3);
    const int bh  = g_ >> 6;
    const int qt  = 63 - (g_ & 63);
    const int qg  = qt * 32 + q32;

    const __bf16* qbase = Qp + (size_t)bh * (64 * 4 * 512) + lane * 8;
    const __bf16* kbase = Kp + (size_t)bh * (64 * 4 * 512) + lane * 8;
    const __bf16* vbase = Vp + (size_t)bh * (64 * 4 * 512) + lane * 8;

    const int b = bh >> 4, h = bh & 15;

    bf16x8 qf[4];
    const __bf16* qp_ = qbase + (size_t)qt * 2048;
    qf[0] = *reinterpret_cast<const bf16x8*>(qp_);
    qf[1] = *reinterpret_cast<const bf16x8*>(qp_ + 512);
    qf[2] = *reinterpret_cast<const bf16x8*>(qp_ + 1024);
    qf[3] = *reinterpret_cast<const bf16x8*>(qp_ + 1536);

    f32x16 o0 = {}, o1 = {};
    float lsum = 0.f;

    bf16x8 kf[4], vf[4];
    for (int t = w; t <= qt; t += 4) {
        ATTN_LOAD(kf, vf, t);
        ATTN_TILE(kf, vf, t, t == qt, qg);
    }

#pragma unroll
    for (int r = 0; r < 16; r += 2) {
        *reinterpret_cast<unsigned*>(&oLs[w][lane][r])      = pack2(o0[r], o0[r + 1]);
        *reinterpret_cast<unsigned*>(&oLs[w][lane][16 + r]) = pack2(o1[r], o1[r + 1]);
    }
    lvL[w][lane] = lsum;
    __syncthreads();

    float Lt = 0.f;
#pragma unroll
    for (int j = 0; j < 4; ++j)
        Lt += lvL[j][q32] + lvL[j][q32 + 32];
    const float inv = 1.0f / Lt;

    __hip_bfloat16* dst = ctx + ((size_t)(b * LLEN + qg)) * DD + h * HDD;
    const int T = w >> 1;
    const int gb = (w & 1) * 2;
#pragma unroll
    for (int g2 = 0; g2 < 2; ++g2) {
        const int g = gb + g2;
        const int rb = T * 16 + 4 * g;
        float acc4[4] = {0.f, 0.f, 0.f, 0.f};
#pragma unroll
        for (int j = 0; j < 4; ++j) {
            unsigned a = *reinterpret_cast<const unsigned*>(&oLs[j][lane][rb]);
            unsigned c = *reinterpret_cast<const unsigned*>(&oLs[j][lane][rb + 2]);
            acc4[0] += bfu((ushort)(a & 0xffff));
            acc4[1] += bfu((ushort)(a >> 16));
            acc4[2] += bfu((ushort)(c & 0xffff));
            acc4[3] += bfu((ushort)(c >> 16));
        }
        ushort st4[4];
#pragma unroll
        for (int e = 0; e < 4; ++e) st4[e] = f2bf(acc4[e] * inv);
        const int d = T * 32 + 8 * g + 4 * hi;
        *reinterpret_cast<ushort4*>(dst + d) = *reinterpret_cast<ushort4*>(st4);
    }
}

// ---------------------------------------------------------------------------
extern "C" void kernel_launch(void* const* d_in, const int* in_sizes, int n_in,
                              void* d_out, int out_size, void* d_ws, size_t ws_size,
                              hipStream_t stream) {
    const float* x    = (const float*)d_in[0];
    const float* wq_w = (const float*)d_in[1];
    const float* wq_b = (const float*)d_in[2];
    const float* wk_w = (const float*)d_in[3];
    const float* wk_b = (const float*)d_in[4];
    const float* wv_w = (const float*)d_in[5];
    const float* wv_b = (const float*)d_in[6];
    const float* wo_w = (const float*)d_in[7];
    const float* wo_b = (const float*)d_in[8];
    float* out = (float*)d_out;

    const size_t MB = 1024 * 1024;
    char* p = (char*)d_ws;
    __bf16* x16   = (__bf16*)p;            p += 8 * MB;   // [4096][1024]
    __bf16* wqkvt = (__bf16*)p;            p += 6 * MB;   // [3072][1024]
    __bf16* wot   = (__bf16*)p;            p += 2 * MB;   // [1024][1024]
    __hip_bfloat16* qp16 = (__hip_bfloat16*)p; p += 8 * MB;  // packed QP (SC2-scaled)
    __hip_bfloat16* kp16 = (__hip_bfloat16*)p; p += 8 * MB;  // packed KP
    __hip_bfloat16* vp16 = (__hip_bfloat16*)p; p += 8 * MB;  // packed VP
    __hip_bfloat16* ctx16 = (__hip_bfloat16*)p;               // [B][L][D]

    hipLaunchKernelGGL(cvt_x_k, dim3(4096), dim3(256), 0, stream, x, (ushort*)x16);
    hipLaunchKernelGGL(wt_cvt_all_k, dim3(16, 16, 4), dim3(256), 0, stream,
                       wq_w, wk_w, wv_w, wo_w, (ushort*)wqkvt, (ushort*)wot);

    // fused QKV projection + RoPE + Q scale fold + Q/K/V fragment packing
    hipLaunchKernelGGL((gemm_mfma_k<1>), dim3(24, 64), dim3(256), 0, stream,
                       x16, wqkvt, wq_b, wk_b, wv_b, (float*)nullptr, qp16, kp16, vp16);

    // attention (single qtile/block, 2048 blocks, heavy-first, split-KV)
    hipLaunchKernelGGL(attn_mfma17_k, dim3(2048), dim3(256), 0, stream,
                       (const __bf16*)qp16, (const __bf16*)kp16, (const __bf16*)vp16, ctx16);

    // output projection (64x64 tiles, 2-phase dbuf)
    hipLaunchKernelGGL((gemm_mfma_k<0>), dim3(16, 64), dim3(256), 0, stream,
                       (const __bf16*)ctx16, wot, wo_b, (const float*)nullptr, (const float*)nullptr,
                       out, (__hip_bfloat16*)nullptr, (__hip_bfloat16*)nullptr, (__hip_bfloat16*)nullptr);
}

// Round 25
// 97.794 us; speedup vs baseline: 1.0693x; 1.0339x over previous
//
#include <hip/hip_runtime.h>
#include <hip/hip_bf16.h>
#include <float.h>
#include <math.h>

// Problem constants: B=2, L=2048, D=1024, NH=16, HD=64
#define BB  2
#define LLEN 2048
#define DD  1024
#define NHH 16
#define HDD 64
#define MROWS (BB * LLEN)   // 4096

typedef __bf16 bf16x8  __attribute__((ext_vector_type(8)));
typedef float  f32x4   __attribute__((ext_vector_type(4)));
typedef float  f32x16  __attribute__((ext_vector_type(16)));
typedef ushort us8     __attribute__((ext_vector_type(8)));

#define EXP2F(x) __builtin_amdgcn_exp2f(x)   // 1-inst v_exp_f32

static __device__ __forceinline__ ushort f2bf(float f) {
    __hip_bfloat16 h = __float2bfloat16(f);
    return *reinterpret_cast<ushort*>(&h);
}
static __device__ __forceinline__ float bfu(ushort u) {
    unsigned x = (unsigned)u << 16;
    return __uint_as_float(x);
}
static __device__ __forceinline__ unsigned pack2(float a, float b) {
    return (unsigned)f2bf(a) | ((unsigned)f2bf(b) << 16);
}

__device__ __forceinline__ void gload16(const void* g, void* l) {
    __builtin_amdgcn_global_load_lds(
        (const __attribute__((address_space(1))) void*)g,
        (__attribute__((address_space(3))) void*)l, 16, 0, 0);
}

// ---------------------------------------------------------------------------
// Weight transposes+converts (z=0..3) + x fp32->bf16 (z=4) in ONE launch.
// (z=4 slice passed correctness in round 23; isolated here on the best base.)
// ---------------------------------------------------------------------------
__global__ __launch_bounds__(256) void wt_cvt_all_k(const float* __restrict__ w0,
                                                    const float* __restrict__ w1,
                                                    const float* __restrict__ w2,
                                                    const float* __restrict__ w3,
                                                    const float* __restrict__ xin,
                                                    ushort* __restrict__ qkv,
                                                    ushort* __restrict__ wo,
                                                    ushort* __restrict__ xout) {
    const int z = blockIdx.z;
    const int tid = threadIdx.x;
    if (z == 4) {
        // x: 4M floats = 1M float4; 256 blocks x 256 thr x 16 float4
        const int bx = blockIdx.y * 16 + blockIdx.x;   // 0..255
        const float4* src = reinterpret_cast<const float4*>(xin);
        ushort4* dst = reinterpret_cast<ushort4*>(xout);
        const int base = bx * 4096 + tid;
#pragma unroll
        for (int it = 0; it < 16; ++it) {
            float4 v = src[base + it * 256];
            ushort4 o;
            o.x = f2bf(v.x); o.y = f2bf(v.y); o.z = f2bf(v.z); o.w = f2bf(v.w);
            dst[base + it * 256] = o;
        }
        return;
    }
    __shared__ float T[64][65];
    const float* in = (z == 0) ? w0 : (z == 1) ? w1 : (z == 2) ? w2 : w3;
    ushort* out = (z < 3) ? (qkv + (size_t)z * 1024 * DD) : wo;

    const int r0 = blockIdx.y * 64, c0 = blockIdx.x * 64;
    for (int i = tid; i < 64 * 16; i += 256) {
        int r = i >> 4, c4 = (i & 15) * 4;
        float4 v = *reinterpret_cast<const float4*>(&in[(size_t)(r0 + r) * DD + c0 + c4]);
        T[r][c4 + 0] = v.x; T[r][c4 + 1] = v.y; T[r][c4 + 2] = v.z; T[r][c4 + 3] = v.w;
    }
    __syncthreads();
    for (int i = tid; i < 64 * 16; i += 256) {
        int rr = i >> 4, cc4 = (i & 15) * 4;
        ushort4 o;
        o.x = f2bf(T[cc4 + 0][rr]);
        o.y = f2bf(T[cc4 + 1][rr]);
        o.z = f2bf(T[cc4 + 2][rr]);
        o.w = f2bf(T[cc4 + 3][rr]);
        *reinterpret_cast<ushort4*>(&out[(size_t)(c0 + rr) * DD + r0 + cc4]) = o;
    }
}

// ---------------------------------------------------------------------------
// bf16 MFMA GEMM: small tiles + 2-PHASE DOUBLE BUFFER (round-22, best).
//   MODE 1 (QKV): 64x128 tile, grid (24,64), LDS 48KB (3 blocks/CU).
//   MODE 0 (out): 64x64 tile,  grid (16,64), LDS 32KB (4 blocks/CU).
// ---------------------------------------------------------------------------
template <int MODE>
__global__ __launch_bounds__(256, 3) void gemm_mfma_k(
    const __bf16* __restrict__ A, const __bf16* __restrict__ Bt,
    const float* __restrict__ bias0, const float* __restrict__ bias1,
    const float* __restrict__ bias2,
    float* __restrict__ out_f32,
    __hip_bfloat16* __restrict__ oq, __hip_bfloat16* __restrict__ ok,
    __hip_bfloat16* __restrict__ ov) {
    constexpr int K  = DD;
    constexpr int NF = (MODE == 1) ? 8 : 4;      // n-frags per wave
    constexpr int BN = NF * 16;                  // tile N: 128 or 64
    constexpr int HALF = (64 + BN) * 64;         // elems per buffer
    __shared__ char smem[2 * HALF * 2];          // 48KB or 32KB
    __bf16* smem_e = (__bf16*)smem;

    const int tid  = threadIdx.x;
    const int w    = tid >> 6;
    const int lane = tid & 63;
    const int lr   = lane & 15;
    const int lg   = lane >> 4;
    const int bm = blockIdx.y * 64, bn = blockIdx.x * BN;

    const int srow8 = lane >> 3;
    const int schk  = (lane & 7) ^ srow8;        // pre-swizzled src chunk
    const __bf16* gA = A  + (size_t)(bm + w * 16 + srow8) * K + schk * 8;
    const __bf16* gB = Bt + (size_t)(bn + w * (NF * 4) + srow8) * K + schk * 8;

    f32x4 acc[NF] = {};
    const int l7 = lr & 7;

    auto STAGE = [&](int buf, int k0) {
        __bf16* base = smem_e + buf * HALF;
        char* lA = (char*)base + w * 16 * 128;
        char* lB = (char*)(base + 4096) + w * (NF * 4) * 128;
#pragma unroll
        for (int c = 0; c < 2; ++c)
            gload16(gA + (size_t)(c * 8) * K + k0, lA + c * 1024);
#pragma unroll
        for (int c = 0; c < NF / 2; ++c)
            gload16(gB + (size_t)(c * 8) * K + k0, lB + c * 1024);
    };

    STAGE(0, 0);
    __syncthreads();
    for (int i = 0; i < 16; ++i) {
        if (i < 15) STAGE((i + 1) & 1, (i + 1) * 64);   // issue-early prefetch
        const __bf16* As_ = smem_e + (i & 1) * HALF;
        const __bf16* Bs_ = As_ + 4096;
#pragma unroll
        for (int kk = 0; kk < 2; ++kk) {
            const int rchk = ((kk * 4 + lg) ^ l7) << 3;
            bf16x8 a = *reinterpret_cast<const bf16x8*>(As_ + (w * 16 + lr) * 64 + rchk);
#pragma unroll
            for (int n = 0; n < NF; ++n) {
                bf16x8 b = *reinterpret_cast<const bf16x8*>(Bs_ + (n * 16 + lr) * 64 + rchk);
                acc[n] = __builtin_amdgcn_mfma_f32_16x16x32_bf16(a, b, acc[n], 0, 0, 0);
            }
        }
        __syncthreads();   // drains prefetch (had full compute phase) + buffer reuse
    }

    if (MODE == 1) {
        const int seg = bn >> 10;
        const int colbase = bn & 1023;
        const int h0 = colbase >> 6;
        const int b  = bm >> 11;
        const int bmL = bm & 2047;
        if (seg == 2) {
#pragma unroll
            for (int n = 0; n < NF; ++n) {
                const int h  = h0 + (n >> 2);
                const int hd = (n & 3) * 16 + lr;
                const float bv = bias2[colbase + n * 16 + lr];
                const int rowb = bm + w * 16 + lg * 4;
                const int l0 = rowb & 2047;
                ushort4 st;
                st.x = f2bf(acc[n][0] + bv);
                st.y = f2bf(acc[n][1] + bv);
                st.z = f2bf(acc[n][2] + bv);
                st.w = f2bf(acc[n][3] + bv);
                const int bh = b * NHH + h;
                const int t  = l0 >> 5;
                const int j  = ((hd >> 5) << 1) | ((l0 >> 4) & 1);
                const int ln = (hd & 31) + ((l0 >> 3) & 1) * 32;
                const int e0 = l0 & 7;
                size_t base = ((((size_t)bh * 64 + t) * 4 + j) * 64 + ln) * 8 + e0;
                *reinterpret_cast<ushort4*>(&ov[base]) = st;
            }
        } else {
            const float* biasp = (seg == 0) ? bias0 : bias1;
            const float osc = (seg == 0) ? 0.18033688011112042f : 1.0f;
            ushort* LP = (ushort*)smem + w * 2048;
#pragma unroll
            for (int hh = 0; hh < 2; ++hh) {
#pragma unroll
                for (int n2 = 0; n2 < 2; ++n2) {
                    const int nA = hh * 4 + n2, nB = nA + 2;
                    const int d  = n2 * 16 + lr;
                    const float tsd = exp2f((float)d * -0.4152410118609203f);
                    const float bv0 = biasp[colbase + hh * 64 + d];
                    const float bv1 = biasp[colbase + hh * 64 + d + 32];
                    const int c0  = d >> 4;
                    const int hi8 = (d >> 3) & 1;
#pragma unroll
                    for (int i = 0; i < 4; ++i) {
                        const int lw = lg * 4 + i;
                        const int l  = bmL + w * 16 + lw;
                        float s, c;
                        __sincosf((float)l * tsd, &s, &c);
                        const float x0 = acc[nA][i] + bv0;
                        const float x1 = acc[nB][i] + bv1;
                        const int lnL = lw + 16 * hi8;
                        LP[hh * 1024 + (c0 * 32 + lnL) * 8 + (d & 7)] =
                            f2bf((x0 * c - x1 * s) * osc);
                        LP[hh * 1024 + ((c0 + 2) * 32 + lnL) * 8 + (d & 7)] =
                            f2bf((x1 * c + x0 * s) * osc);
                    }
                }
            }
            __syncthreads();
            ushort* dstp = (ushort*)((seg == 0) ? oq : ok);
            const int t   = (bmL >> 5) + (w >> 1);
            const int r0w = (w & 1) * 16;
#pragma unroll
            for (int hh = 0; hh < 2; ++hh) {
                const int bh = b * NHH + h0 + hh;
#pragma unroll
                for (int it = 0; it < 2; ++it) {
                    const int f = it * 64 + lane;
                    const int c = f >> 5, lnL = f & 31;
                    const int ln = r0w + (lnL & 15) + 32 * (lnL >> 4);
                    us8 v = *reinterpret_cast<const us8*>(&LP[hh * 1024 + f * 8]);
                    size_t base = ((((size_t)bh * 64 + t) * 4 + c) * 64 + ln) * 8;
                    *reinterpret_cast<us8*>(&dstp[base]) = v;
                }
            }
        }
    } else {
        float* FP = (float*)smem + w * 1024;
        __syncthreads();
#pragma unroll
        for (int n = 0; n < NF; ++n) {
            const int col = n * 16 + lr;
            const float bv = bias0[bn + col];
#pragma unroll
            for (int i = 0; i < 4; ++i)
                FP[(lg * 4 + i) * 64 + col] = acc[n][i] + bv;
        }
        __syncthreads();
#pragma unroll
        for (int it = 0; it < 4; ++it) {
            const int f = it * 64 + lane;
            const int row16 = f >> 4, cq = f & 15;
            float4 v = *reinterpret_cast<const float4*>(&FP[row16 * 64 + cq * 4]);
            const int row = bm + w * 16 + row16;
            *reinterpret_cast<float4*>(&out_f32[(size_t)row * DD + bn + cq * 4]) = v;
        }
    }
}

// ---------------------------------------------------------------------------
// Flash attention (causal), swapped-operand 32x32 MFMA, packed Q/K/V,
// no-max softmax, bf16 LDS partials. 2048 blocks = one qtile per block,
// heavy-first per XCD (LPT). (round-21/22/24, passing)
// ---------------------------------------------------------------------------
#define ATTN_LOAD(KF, VF, T0)                                                   \
    do {                                                                        \
        const __bf16* kp_ = kbase + (size_t)(T0) * 2048;                        \
        KF[0] = *reinterpret_cast<const bf16x8*>(kp_);                          \
        KF[1] = *reinterpret_cast<const bf16x8*>(kp_ + 512);                    \
        KF[2] = *reinterpret_cast<const bf16x8*>(kp_ + 1024);                   \
        KF[3] = *reinterpret_cast<const bf16x8*>(kp_ + 1536);                   \
        const __bf16* vp_ = vbase + (size_t)(T0) * 2048;                        \
        VF[0] = *reinterpret_cast<const bf16x8*>(vp_);                          \
        VF[1] = *reinterpret_cast<const bf16x8*>(vp_ + 512);                    \
        VF[2] = *reinterpret_cast<const bf16x8*>(vp_ + 1024);                   \
        VF[3] = *reinterpret_cast<const bf16x8*>(vp_ + 1536);                   \
    } while (0)

#define ATTN_TILE(KF, VF, T0, MASKIT, QG)                                       \
    do {                                                                        \
        f32x16 s_ = {};                                                         \
        __builtin_amdgcn_s_setprio(1);                                          \
        s_ = __builtin_amdgcn_mfma_f32_32x32x16_bf16(KF[0], qf[0], s_, 0, 0, 0);\
        s_ = __builtin_amdgcn_mfma_f32_32x32x16_bf16(KF[1], qf[1], s_, 0, 0, 0);\
        s_ = __builtin_amdgcn_mfma_f32_32x32x16_bf16(KF[2], qf[2], s_, 0, 0, 0);\
        s_ = __builtin_amdgcn_mfma_f32_32x32x16_bf16(KF[3], qf[3], s_, 0, 0, 0);\
        __builtin_amdgcn_s_setprio(0);                                          \
        float p_[16];                                                           \
        const int k0_ = (T0) * 32;                                              \
        if (MASKIT) {                                                           \
            _Pragma("unroll")                                                   \
            for (int i = 0; i < 16; ++i) {                                      \
                int kkg_ = k0_ + (i & 3) + 8 * (i >> 2) + 4 * hi;               \
                p_[i] = (kkg_ <= (QG)) ? EXP2F(s_[i]) : 0.f;                    \
            }                                                                   \
        } else {                                                                \
            _Pragma("unroll")                                                   \
            for (int i = 0; i < 16; ++i) p_[i] = EXP2F(s_[i]);                  \
        }                                                                       \
        _Pragma("unroll")                                                       \
        for (int i = 0; i < 16; ++i) lsum += p_[i];                             \
        unsigned u_[8], x_[8];                                                  \
        _Pragma("unroll")                                                       \
        for (int j = 0; j < 8; ++j)                                             \
            u_[j] = pack2(p_[2 * j], p_[2 * j + 1]);                            \
        _Pragma("unroll")                                                       \
        for (int j = 0; j < 8; ++j)                                             \
            x_[j] = (unsigned)__shfl_xor((int)u_[j], 32);                       \
        union { unsigned d[4]; bf16x8 v; } B1_, B2_;                            \
        if (hi == 0) {                                                          \
            B1_.d[0] = u_[0]; B1_.d[1] = u_[1]; B1_.d[2] = x_[0]; B1_.d[3] = x_[1]; \
            B2_.d[0] = u_[4]; B2_.d[1] = u_[5]; B2_.d[2] = x_[4]; B2_.d[3] = x_[5]; \
        } else {                                                                \
            B1_.d[0] = x_[2]; B1_.d[1] = x_[3]; B1_.d[2] = u_[2]; B1_.d[3] = u_[3]; \
            B2_.d[0] = x_[6]; B2_.d[1] = x_[7]; B2_.d[2] = u_[6]; B2_.d[3] = u_[7]; \
        }                                                                       \
        __builtin_amdgcn_s_setprio(1);                                          \
        o0 = __builtin_amdgcn_mfma_f32_32x32x16_bf16(VF[0], B1_.v, o0, 0, 0, 0);\
        o0 = __builtin_amdgcn_mfma_f32_32x32x16_bf16(VF[1], B2_.v, o0, 0, 0, 0);\
        o1 = __builtin_amdgcn_mfma_f32_32x32x16_bf16(VF[2], B1_.v, o1, 0, 0, 0);\
        o1 = __builtin_amdgcn_mfma_f32_32x32x16_bf16(VF[3], B2_.v, o1, 0, 0, 0);\
        __builtin_amdgcn_s_setprio(0);                                          \
    } while (0)

__global__ __launch_bounds__(256) void attn_mfma17_k(const __bf16* __restrict__ Qp,
                                                     const __bf16* __restrict__ Kp,
                                                     const __bf16* __restrict__ Vp,
                                                     __hip_bfloat16* __restrict__ ctx) {
    __shared__ ushort oLs[4][64][34];
    __shared__ float lvL[4][64];

    const int tid  = threadIdx.x;
    const int w    = tid >> 6;
    const int lane = tid & 63;
    const int q32  = lane & 31;
    const int hi   = lane >> 5;

    const int bid = blockIdx.x;
    const int g_  = (bid & 7) * 256 + (bid >> 3);
    const int bh  = g_ >> 6;
    const int qt  = 63 - (g_ & 63);
    const int qg  = qt * 32 + q32;

    const __bf16* qbase = Qp + (size_t)bh * (64 * 4 * 512) + lane * 8;
    const __bf16* kbase = Kp + (size_t)bh * (64 * 4 * 512) + lane * 8;
    const __bf16* vbase = Vp + (size_t)bh * (64 * 4 * 512) + lane * 8;

    const int b = bh >> 4, h = bh & 15;

    bf16x8 qf[4];
    const __bf16* qp_ = qbase + (size_t)qt * 2048;
    qf[0] = *reinterpret_cast<const bf16x8*>(qp_);
    qf[1] = *reinterpret_cast<const bf16x8*>(qp_ + 512);
    qf[2] = *reinterpret_cast<const bf16x8*>(qp_ + 1024);
    qf[3] = *reinterpret_cast<const bf16x8*>(qp_ + 1536);

    f32x16 o0 = {}, o1 = {};
    float lsum = 0.f;

    bf16x8 kf[4], vf[4];
    for (int t = w; t <= qt; t += 4) {
        ATTN_LOAD(kf, vf, t);
        ATTN_TILE(kf, vf, t, t == qt, qg);
    }

#pragma unroll
    for (int r = 0; r < 16; r += 2) {
        *reinterpret_cast<unsigned*>(&oLs[w][lane][r])      = pack2(o0[r], o0[r + 1]);
        *reinterpret_cast<unsigned*>(&oLs[w][lane][16 + r]) = pack2(o1[r], o1[r + 1]);
    }
    lvL[w][lane] = lsum;
    __syncthreads();

    float Lt = 0.f;
#pragma unroll
    for (int j = 0; j < 4; ++j)
        Lt += lvL[j][q32] + lvL[j][q32 + 32];
    const float inv = 1.0f / Lt;

    __hip_bfloat16* dst = ctx + ((size_t)(b * LLEN + qg)) * DD + h * HDD;
    const int T = w >> 1;
    const int gb = (w & 1) * 2;
#pragma unroll
    for (int g2 = 0; g2 < 2; ++g2) {
        const int g = gb + g2;
        const int rb = T * 16 + 4 * g;
        float acc4[4] = {0.f, 0.f, 0.f, 0.f};
#pragma unroll
        for (int j = 0; j < 4; ++j) {
            unsigned a = *reinterpret_cast<const unsigned*>(&oLs[j][lane][rb]);
            unsigned c = *reinterpret_cast<const unsigned*>(&oLs[j][lane][rb + 2]);
            acc4[0] += bfu((ushort)(a & 0xffff));
            acc4[1] += bfu((ushort)(a >> 16));
            acc4[2] += bfu((ushort)(c & 0xffff));
            acc4[3] += bfu((ushort)(c >> 16));
        }
        ushort st4[4];
#pragma unroll
        for (int e = 0; e < 4; ++e) st4[e] = f2bf(acc4[e] * inv);
        const int d = T * 32 + 8 * g + 4 * hi;
        *reinterpret_cast<ushort4*>(dst + d) = *reinterpret_cast<ushort4*>(st4);
    }
}

// ---------------------------------------------------------------------------
extern "C" void kernel_launch(void* const* d_in, const int* in_sizes, int n_in,
                              void* d_out, int out_size, void* d_ws, size_t ws_size,
                              hipStream_t stream) {
    const float* x    = (const float*)d_in[0];
    const float* wq_w = (const float*)d_in[1];
    const float* wq_b = (const float*)d_in[2];
    const float* wk_w = (const float*)d_in[3];
    const float* wk_b = (const float*)d_in[4];
    const float* wv_w = (const float*)d_in[5];
    const float* wv_b = (const float*)d_in[6];
    const float* wo_w = (const float*)d_in[7];
    const float* wo_b = (const float*)d_in[8];
    float* out = (float*)d_out;

    const size_t MB = 1024 * 1024;
    char* p = (char*)d_ws;
    __bf16* x16   = (__bf16*)p;            p += 8 * MB;   // [4096][1024]
    __bf16* wqkvt = (__bf16*)p;            p += 6 * MB;   // [3072][1024]
    __bf16* wot   = (__bf16*)p;            p += 2 * MB;   // [1024][1024]
    __hip_bfloat16* qp16 = (__hip_bfloat16*)p; p += 8 * MB;  // packed QP (SC2-scaled)
    __hip_bfloat16* kp16 = (__hip_bfloat16*)p; p += 8 * MB;  // packed KP
    __hip_bfloat16* vp16 = (__hip_bfloat16*)p; p += 8 * MB;  // packed VP
    __hip_bfloat16* ctx16 = (__hip_bfloat16*)p;               // [B][L][D]

    // weight transposes + x conversion (ONE launch, z=0..4)
    hipLaunchKernelGGL(wt_cvt_all_k, dim3(16, 16, 5), dim3(256), 0, stream,
                       wq_w, wk_w, wv_w, wo_w, x,
                       (ushort*)wqkvt, (ushort*)wot, (ushort*)x16);

    // fused QKV projection + RoPE + Q scale fold + Q/K/V fragment packing
    hipLaunchKernelGGL((gemm_mfma_k<1>), dim3(24, 64), dim3(256), 0, stream,
                       x16, wqkvt, wq_b, wk_b, wv_b, (float*)nullptr, qp16, kp16, vp16);

    // attention (single qtile/block, 2048 blocks, heavy-first, split-KV)
    hipLaunchKernelGGL(attn_mfma17_k, dim3(2048), dim3(256), 0, stream,
                       (const __bf16*)qp16, (const __bf16*)kp16, (const __bf16*)vp16, ctx16);

    // output projection (64x64 tiles, 2-phase dbuf)
    hipLaunchKernelGGL((gemm_mfma_k<0>), dim3(16, 64), dim3(256), 0, stream,
                       (const __bf16*)ctx16, wot, wo_b, (const float*)nullptr, (const float*)nullptr,
                       out, (__hip_bfloat16*)nullptr, (__hip_bfloat16*)nullptr, (__hip_bfloat16*)nullptr);
}

// Round 26
// 97.339 us; speedup vs baseline: 1.0743x; 1.0047x over previous
//
#include <hip/hip_runtime.h>
#include <hip/hip_bf16.h>
#include <float.h>
#include <math.h>

// Problem constants: B=2, L=2048, D=1024, NH=16, HD=64
#define BB  2
#define LLEN 2048
#define DD  1024
#define NHH 16
#define HDD 64
#define MROWS (BB * LLEN)   // 4096

typedef __bf16 bf16x8  __attribute__((ext_vector_type(8)));
typedef float  f32x4   __attribute__((ext_vector_type(4)));
typedef float  f32x16  __attribute__((ext_vector_type(16)));
typedef ushort us8     __attribute__((ext_vector_type(8)));

#define EXP2F(x) __builtin_amdgcn_exp2f(x)   // 1-inst v_exp_f32

static __device__ __forceinline__ ushort f2bf(float f) {
    __hip_bfloat16 h = __float2bfloat16(f);
    return *reinterpret_cast<ushort*>(&h);
}
static __device__ __forceinline__ float bfu(ushort u) {
    unsigned x = (unsigned)u << 16;
    return __uint_as_float(x);
}
static __device__ __forceinline__ unsigned pack2(float a, float b) {
    return (unsigned)f2bf(a) | ((unsigned)f2bf(b) << 16);
}

__device__ __forceinline__ void gload16(const void* g, void* l) {
    __builtin_amdgcn_global_load_lds(
        (const __attribute__((address_space(1))) void*)g,
        (__attribute__((address_space(3))) void*)l, 16, 0, 0);
}

// ---------------------------------------------------------------------------
// Weight transposes+converts (z=0..3) + x fp32->bf16 (z=4) in ONE launch.
// ---------------------------------------------------------------------------
__global__ __launch_bounds__(256) void wt_cvt_all_k(const float* __restrict__ w0,
                                                    const float* __restrict__ w1,
                                                    const float* __restrict__ w2,
                                                    const float* __restrict__ w3,
                                                    const float* __restrict__ xin,
                                                    ushort* __restrict__ qkv,
                                                    ushort* __restrict__ wo,
                                                    ushort* __restrict__ xout) {
    const int z = blockIdx.z;
    const int tid = threadIdx.x;
    if (z == 4) {
        const int bx = blockIdx.y * 16 + blockIdx.x;   // 0..255
        const float4* src = reinterpret_cast<const float4*>(xin);
        ushort4* dst = reinterpret_cast<ushort4*>(xout);
        const int base = bx * 4096 + tid;
#pragma unroll
        for (int it = 0; it < 16; ++it) {
            float4 v = src[base + it * 256];
            ushort4 o;
            o.x = f2bf(v.x); o.y = f2bf(v.y); o.z = f2bf(v.z); o.w = f2bf(v.w);
            dst[base + it * 256] = o;
        }
        return;
    }
    __shared__ float T[64][65];
    const float* in = (z == 0) ? w0 : (z == 1) ? w1 : (z == 2) ? w2 : w3;
    ushort* out = (z < 3) ? (qkv + (size_t)z * 1024 * DD) : wo;

    const int r0 = blockIdx.y * 64, c0 = blockIdx.x * 64;
    for (int i = tid; i < 64 * 16; i += 256) {
        int r = i >> 4, c4 = (i & 15) * 4;
        float4 v = *reinterpret_cast<const float4*>(&in[(size_t)(r0 + r) * DD + c0 + c4]);
        T[r][c4 + 0] = v.x; T[r][c4 + 1] = v.y; T[r][c4 + 2] = v.z; T[r][c4 + 3] = v.w;
    }
    __syncthreads();
    for (int i = tid; i < 64 * 16; i += 256) {
        int rr = i >> 4, cc4 = (i & 15) * 4;
        ushort4 o;
        o.x = f2bf(T[cc4 + 0][rr]);
        o.y = f2bf(T[cc4 + 1][rr]);
        o.z = f2bf(T[cc4 + 2][rr]);
        o.w = f2bf(T[cc4 + 3][rr]);
        *reinterpret_cast<ushort4*>(&out[(size_t)(c0 + rr) * DD + r0 + cc4]) = o;
    }
}

// ---------------------------------------------------------------------------
// bf16 MFMA GEMM.
//   MODE 1 (QKV): 64x256 tile (NF=16), grid (12,64), single-buffer 40KB
//                 (4 blocks/CU). Doubles MFMA-per-barrier vs 64x128 at same
//                 A traffic -> raises matrix-work/latency ratio.
//   MODE 0 (out): 64x64 tile (NF=4), grid (16,64), 2-phase dbuf 32KB (proven).
// Epilogues: head loop generalized hh < NF/4; formulas identical to the
// rounds-20..25 proven versions.
// ---------------------------------------------------------------------------
template <int MODE>
__global__ __launch_bounds__(256, MODE == 1 ? 4 : 3) void gemm_mfma_k(
    const __bf16* __restrict__ A, const __bf16* __restrict__ Bt,
    const float* __restrict__ bias0, const float* __restrict__ bias1,
    const float* __restrict__ bias2,
    float* __restrict__ out_f32,
    __hip_bfloat16* __restrict__ oq, __hip_bfloat16* __restrict__ ok,
    __hip_bfloat16* __restrict__ ov) {
    constexpr int K  = DD;
    constexpr int NF = (MODE == 1) ? 16 : 4;     // n-frags per wave
    constexpr int BN = NF * 16;                  // tile N: 256 or 64
    constexpr int HALF = (64 + BN) * 64;         // elems per buffer
    constexpr int NBUF = (MODE == 1) ? 1 : 2;
    __shared__ char smem[NBUF * HALF * 2];       // 40KB or 32KB
    __bf16* smem_e = (__bf16*)smem;

    const int tid  = threadIdx.x;
    const int w    = tid >> 6;
    const int lane = tid & 63;
    const int lr   = lane & 15;
    const int lg   = lane >> 4;
    const int bm = blockIdx.y * 64, bn = blockIdx.x * BN;

    const int srow8 = lane >> 3;
    const int schk  = (lane & 7) ^ srow8;        // pre-swizzled src chunk
    const __bf16* gA = A  + (size_t)(bm + w * 16 + srow8) * K + schk * 8;
    const __bf16* gB = Bt + (size_t)(bn + w * (NF * 4) + srow8) * K + schk * 8;

    f32x4 acc[NF] = {};
    const int l7 = lr & 7;

    auto STAGE = [&](int buf, int k0) {
        __bf16* base = smem_e + buf * HALF;
        char* lA = (char*)base + w * 16 * 128;
        char* lB = (char*)(base + 4096) + w * (NF * 4) * 128;
#pragma unroll
        for (int c = 0; c < 2; ++c)
            gload16(gA + (size_t)(c * 8) * K + k0, lA + c * 1024);
#pragma unroll
        for (int c = 0; c < NF / 2; ++c)
            gload16(gB + (size_t)(c * 8) * K + k0, lB + c * 1024);
    };

    auto COMPUTE = [&](const __bf16* As_) {
        const __bf16* Bs_ = As_ + 4096;
#pragma unroll
        for (int kk = 0; kk < 2; ++kk) {
            const int rchk = ((kk * 4 + lg) ^ l7) << 3;
            bf16x8 a = *reinterpret_cast<const bf16x8*>(As_ + (w * 16 + lr) * 64 + rchk);
#pragma unroll
            for (int n = 0; n < NF; ++n) {
                bf16x8 b = *reinterpret_cast<const bf16x8*>(Bs_ + (n * 16 + lr) * 64 + rchk);
                acc[n] = __builtin_amdgcn_mfma_f32_16x16x32_bf16(a, b, acc[n], 0, 0, 0);
            }
        }
    };

    if constexpr (MODE == 1) {
        // single-buffer, 2-barrier (round-20 proven structure)
        for (int k0 = 0; k0 < K; k0 += 64) {
            STAGE(0, k0);
            __syncthreads();
            COMPUTE(smem_e);
            __syncthreads();
        }
    } else {
        // 2-phase double buffer (round-22 proven structure)
        STAGE(0, 0);
        __syncthreads();
        for (int i = 0; i < 16; ++i) {
            if (i < 15) STAGE((i + 1) & 1, (i + 1) * 64);
            COMPUTE(smem_e + (i & 1) * HALF);
            __syncthreads();
        }
    }

    if (MODE == 1) {
        const int seg = bn >> 10;                  // 0=Q,1=K,2=V (4 blocks/seg)
        const int colbase = bn & 1023;             // 0,256,512,768
        const int h0 = colbase >> 6;
        const int b  = bm >> 11;
        const int bmL = bm & 2047;
        if (seg == 2) {
#pragma unroll
            for (int n = 0; n < NF; ++n) {
                const int h  = h0 + (n >> 2);
                const int hd = (n & 3) * 16 + lr;
                const float bv = bias2[colbase + n * 16 + lr];
                const int rowb = bm + w * 16 + lg * 4;
                const int l0 = rowb & 2047;
                ushort4 st;
                st.x = f2bf(acc[n][0] + bv);
                st.y = f2bf(acc[n][1] + bv);
                st.z = f2bf(acc[n][2] + bv);
                st.w = f2bf(acc[n][3] + bv);
                const int bh = b * NHH + h;
                const int t  = l0 >> 5;
                const int j  = ((hd >> 5) << 1) | ((l0 >> 4) & 1);
                const int ln = (hd & 31) + ((l0 >> 3) & 1) * 32;
                const int e0 = l0 & 7;
                size_t base = ((((size_t)bh * 64 + t) * 4 + j) * 64 + ln) * 8 + e0;
                *reinterpret_cast<ushort4*>(&ov[base]) = st;
            }
        } else {
            const float* biasp = (seg == 0) ? bias0 : bias1;
            const float osc = (seg == 0) ? 0.18033688011112042f : 1.0f;
            ushort* LP = (ushort*)smem + w * 4096;   // 8KB/wave (NF/4 = 4 heads)
            __syncthreads();
#pragma unroll
            for (int hh = 0; hh < NF / 4; ++hh) {
#pragma unroll
                for (int n2 = 0; n2 < 2; ++n2) {
                    const int nA = hh * 4 + n2, nB = nA + 2;
                    const int d  = n2 * 16 + lr;
                    const float tsd = exp2f((float)d * -0.4152410118609203f);
                    const float bv0 = biasp[colbase + hh * 64 + d];
                    const float bv1 = biasp[colbase + hh * 64 + d + 32];
                    const int c0  = d >> 4;
                    const int hi8 = (d >> 3) & 1;
#pragma unroll
                    for (int i = 0; i < 4; ++i) {
                        const int lw = lg * 4 + i;
                        const int l  = bmL + w * 16 + lw;
                        float s, c;
                        __sincosf((float)l * tsd, &s, &c);
                        const float x0 = acc[nA][i] + bv0;
                        const float x1 = acc[nB][i] + bv1;
                        const int lnL = lw + 16 * hi8;
                        LP[hh * 1024 + (c0 * 32 + lnL) * 8 + (d & 7)] =
                            f2bf((x0 * c - x1 * s) * osc);
                        LP[hh * 1024 + ((c0 + 2) * 32 + lnL) * 8 + (d & 7)] =
                            f2bf((x1 * c + x0 * s) * osc);
                    }
                }
            }
            __syncthreads();
            ushort* dstp = (ushort*)((seg == 0) ? oq : ok);
            const int t   = (bmL >> 5) + (w >> 1);
            const int r0w = (w & 1) * 16;
#pragma unroll
            for (int hh = 0; hh < NF / 4; ++hh) {
                const int bh = b * NHH + h0 + hh;
#pragma unroll
                for (int it = 0; it < 2; ++it) {
                    const int f = it * 64 + lane;
                    const int c = f >> 5, lnL = f & 31;
                    const int ln = r0w + (lnL & 15) + 32 * (lnL >> 4);
                    us8 v = *reinterpret_cast<const us8*>(&LP[hh * 1024 + f * 8]);
                    size_t base = ((((size_t)bh * 64 + t) * 4 + c) * 64 + ln) * 8;
                    *reinterpret_cast<us8*>(&dstp[base]) = v;
                }
            }
        }
    } else {
        float* FP = (float*)smem + w * 1024;
        __syncthreads();
#pragma unroll
        for (int n = 0; n < NF; ++n) {
            const int col = n * 16 + lr;
            const float bv = bias0[bn + col];
#pragma unroll
            for (int i = 0; i < 4; ++i)
                FP[(lg * 4 + i) * 64 + col] = acc[n][i] + bv;
        }
        __syncthreads();
#pragma unroll
        for (int it = 0; it < 4; ++it) {
            const int f = it * 64 + lane;
            const int row16 = f >> 4, cq = f & 15;
            float4 v = *reinterpret_cast<const float4*>(&FP[row16 * 64 + cq * 4]);
            const int row = bm + w * 16 + row16;
            *reinterpret_cast<float4*>(&out_f32[(size_t)row * DD + bn + cq * 4]) = v;
        }
    }
}

// ---------------------------------------------------------------------------
// Flash attention (causal), swapped-operand 32x32 MFMA, packed Q/K/V,
// no-max softmax, bf16 LDS partials. 2048 blocks = one qtile per block,
// heavy-first per XCD (LPT). (rounds 21-25, passing)
// ---------------------------------------------------------------------------
#define ATTN_LOAD(KF, VF, T0)                                                   \
    do {                                                                        \
        const __bf16* kp_ = kbase + (size_t)(T0) * 2048;                        \
        KF[0] = *reinterpret_cast<const bf16x8*>(kp_);                          \
        KF[1] = *reinterpret_cast<const bf16x8*>(kp_ + 512);                    \
        KF[2] = *reinterpret_cast<const bf16x8*>(kp_ + 1024);                   \
        KF[3] = *reinterpret_cast<const bf16x8*>(kp_ + 1536);                   \
        const __bf16* vp_ = vbase + (size_t)(T0) * 2048;                        \
        VF[0] = *reinterpret_cast<const bf16x8*>(vp_);                          \
        VF[1] = *reinterpret_cast<const bf16x8*>(vp_ + 512);                    \
        VF[2] = *reinterpret_cast<const bf16x8*>(vp_ + 1024);                   \
        VF[3] = *reinterpret_cast<const bf16x8*>(vp_ + 1536);                   \
    } while (0)

#define ATTN_TILE(KF, VF, T0, MASKIT, QG)                                       \
    do {                                                                        \
        f32x16 s_ = {};                                                         \
        __builtin_amdgcn_s_setprio(1);                                          \
        s_ = __builtin_amdgcn_mfma_f32_32x32x16_bf16(KF[0], qf[0], s_, 0, 0, 0);\
        s_ = __builtin_amdgcn_mfma_f32_32x32x16_bf16(KF[1], qf[1], s_, 0, 0, 0);\
        s_ = __builtin_amdgcn_mfma_f32_32x32x16_bf16(KF[2], qf[2], s_, 0, 0, 0);\
        s_ = __builtin_amdgcn_mfma_f32_32x32x16_bf16(KF[3], qf[3], s_, 0, 0, 0);\
        __builtin_amdgcn_s_setprio(0);                                          \
        float p_[16];                                                           \
        const int k0_ = (T0) * 32;                                              \
        if (MASKIT) {                                                           \
            _Pragma("unroll")                                                   \
            for (int i = 0; i < 16; ++i) {                                      \
                int kkg_ = k0_ + (i & 3) + 8 * (i >> 2) + 4 * hi;               \
                p_[i] = (kkg_ <= (QG)) ? EXP2F(s_[i]) : 0.f;                    \
            }                                                                   \
        } else {                                                                \
            _Pragma("unroll")                                                   \
            for (int i = 0; i < 16; ++i) p_[i] = EXP2F(s_[i]);                  \
        }                                                                       \
        _Pragma("unroll")                                                       \
        for (int i = 0; i < 16; ++i) lsum += p_[i];                             \
        unsigned u_[8], x_[8];                                                  \
        _Pragma("unroll")                                                       \
        for (int j = 0; j < 8; ++j)                                             \
            u_[j] = pack2(p_[2 * j], p_[2 * j + 1]);                            \
        _Pragma("unroll")                                                       \
        for (int j = 0; j < 8; ++j)                                             \
            x_[j] = (unsigned)__shfl_xor((int)u_[j], 32);                       \
        union { unsigned d[4]; bf16x8 v; } B1_, B2_;                            \
        if (hi == 0) {                                                          \
            B1_.d[0] = u_[0]; B1_.d[1] = u_[1]; B1_.d[2] = x_[0]; B1_.d[3] = x_[1]; \
            B2_.d[0] = u_[4]; B2_.d[1] = u_[5]; B2_.d[2] = x_[4]; B2_.d[3] = x_[5]; \
        } else {                                                                \
            B1_.d[0] = x_[2]; B1_.d[1] = x_[3]; B1_.d[2] = u_[2]; B1_.d[3] = u_[3]; \
            B2_.d[0] = x_[6]; B2_.d[1] = x_[7]; B2_.d[2] = u_[6]; B2_.d[3] = u_[7]; \
        }                                                                       \
        __builtin_amdgcn_s_setprio(1);                                          \
        o0 = __builtin_amdgcn_mfma_f32_32x32x16_bf16(VF[0], B1_.v, o0, 0, 0, 0);\
        o0 = __builtin_amdgcn_mfma_f32_32x32x16_bf16(VF[1], B2_.v, o0, 0, 0, 0);\
        o1 = __builtin_amdgcn_mfma_f32_32x32x16_bf16(VF[2], B1_.v, o1, 0, 0, 0);\
        o1 = __builtin_amdgcn_mfma_f32_32x32x16_bf16(VF[3], B2_.v, o1, 0, 0, 0);\
        __builtin_amdgcn_s_setprio(0);                                          \
    } while (0)

__global__ __launch_bounds__(256) void attn_mfma17_k(const __bf16* __restrict__ Qp,
                                                     const __bf16* __restrict__ Kp,
                                                     const __bf16* __restrict__ Vp,
                                                     __hip_bfloat16* __restrict__ ctx) {
    __shared__ ushort oLs[4][64][34];
    __shared__ float lvL[4][64];

    const int tid  = threadIdx.x;
    const int w    = tid >> 6;
    const int lane = tid & 63;
    const int q32  = lane & 31;
    const int hi   = lane >> 5;

    const int bid = blockIdx.x;
    const int g_  = (bid & 7) * 256 + (bid >> 3);
    const int bh  = g_ >> 6;
    const int qt  = 63 - (g_ & 63);
    const int qg  = qt * 32 + q32;

    const __bf16* qbase = Qp + (size_t)bh * (64 * 4 * 512) + lane * 8;
    const __bf16* kbase = Kp + (size_t)bh * (64 * 4 * 512) + lane * 8;
    const __bf16* vbase = Vp + (size_t)bh * (64 * 4 * 512) + lane * 8;

    const int b = bh >> 4, h = bh & 15;

    bf16x8 qf[4];
    const __bf16* qp_ = qbase + (size_t)qt * 2048;
    qf[0] = *reinterpret_cast<const bf16x8*>(qp_);
    qf[1] = *reinterpret_cast<const bf16x8*>(qp_ + 512);
    qf[2] = *reinterpret_cast<const bf16x8*>(qp_ + 1024);
    qf[3] = *reinterpret_cast<const bf16x8*>(qp_ + 1536);

    f32x16 o0 = {}, o1 = {};
    float lsum = 0.f;

    bf16x8 kf[4], vf[4];
    for (int t = w; t <= qt; t += 4) {
        ATTN_LOAD(kf, vf, t);
        ATTN_TILE(kf, vf, t, t == qt, qg);
    }

#pragma unroll
    for (int r = 0; r < 16; r += 2) {
        *reinterpret_cast<unsigned*>(&oLs[w][lane][r])      = pack2(o0[r], o0[r + 1]);
        *reinterpret_cast<unsigned*>(&oLs[w][lane][16 + r]) = pack2(o1[r], o1[r + 1]);
    }
    lvL[w][lane] = lsum;
    __syncthreads();

    float Lt = 0.f;
#pragma unroll
    for (int j = 0; j < 4; ++j)
        Lt += lvL[j][q32] + lvL[j][q32 + 32];
    const float inv = 1.0f / Lt;

    __hip_bfloat16* dst = ctx + ((size_t)(b * LLEN + qg)) * DD + h * HDD;
    const int T = w >> 1;
    const int gb = (w & 1) * 2;
#pragma unroll
    for (int g2 = 0; g2 < 2; ++g2) {
        const int g = gb + g2;
        const int rb = T * 16 + 4 * g;
        float acc4[4] = {0.f, 0.f, 0.f, 0.f};
#pragma unroll
        for (int j = 0; j < 4; ++j) {
            unsigned a = *reinterpret_cast<const unsigned*>(&oLs[j][lane][rb]);
            unsigned c = *reinterpret_cast<const unsigned*>(&oLs[j][lane][rb + 2]);
            acc4[0] += bfu((ushort)(a & 0xffff));
            acc4[1] += bfu((ushort)(a >> 16));
            acc4[2] += bfu((ushort)(c & 0xffff));
            acc4[3] += bfu((ushort)(c >> 16));
        }
        ushort st4[4];
#pragma unroll
        for (int e = 0; e < 4; ++e) st4[e] = f2bf(acc4[e] * inv);
        const int d = T * 32 + 8 * g + 4 * hi;
        *reinterpret_cast<ushort4*>(dst + d) = *reinterpret_cast<ushort4*>(st4);
    }
}

// ---------------------------------------------------------------------------
extern "C" void kernel_launch(void* const* d_in, const int* in_sizes, int n_in,
                              void* d_out, int out_size, void* d_ws, size_t ws_size,
                              hipStream_t stream) {
    const float* x    = (const float*)d_in[0];
    const float* wq_w = (const float*)d_in[1];
    const float* wq_b = (const float*)d_in[2];
    const float* wk_w = (const float*)d_in[3];
    const float* wk_b = (const float*)d_in[4];
    const float* wv_w = (const float*)d_in[5];
    const float* wv_b = (const float*)d_in[6];
    const float* wo_w = (const float*)d_in[7];
    const float* wo_b = (const float*)d_in[8];
    float* out = (float*)d_out;

    const size_t MB = 1024 * 1024;
    char* p = (char*)d_ws;
    __bf16* x16   = (__bf16*)p;            p += 8 * MB;   // [4096][1024]
    __bf16* wqkvt = (__bf16*)p;            p += 6 * MB;   // [3072][1024]
    __bf16* wot   = (__bf16*)p;            p += 2 * MB;   // [1024][1024]
    __hip_bfloat16* qp16 = (__hip_bfloat16*)p; p += 8 * MB;  // packed QP (SC2-scaled)
    __hip_bfloat16* kp16 = (__hip_bfloat16*)p; p += 8 * MB;  // packed KP
    __hip_bfloat16* vp16 = (__hip_bfloat16*)p; p += 8 * MB;  // packed VP
    __hip_bfloat16* ctx16 = (__hip_bfloat16*)p;               // [B][L][D]

    // weight transposes + x conversion (ONE launch, z=0..4)
    hipLaunchKernelGGL(wt_cvt_all_k, dim3(16, 16, 5), dim3(256), 0, stream,
                       wq_w, wk_w, wv_w, wo_w, x,
                       (ushort*)wqkvt, (ushort*)wot, (ushort*)x16);

    // fused QKV projection + RoPE + Q scale fold + Q/K/V fragment packing
    // (64x256 tiles, grid 12x64)
    hipLaunchKernelGGL((gemm_mfma_k<1>), dim3(12, 64), dim3(256), 0, stream,
                       x16, wqkvt, wq_b, wk_b, wv_b, (float*)nullptr, qp16, kp16, vp16);

    // attention (single qtile/block, 2048 blocks, heavy-first, split-KV)
    hipLaunchKernelGGL(attn_mfma17_k, dim3(2048), dim3(256), 0, stream,
                       (const __bf16*)qp16, (const __bf16*)kp16, (const __bf16*)vp16, ctx16);

    // output projection (64x64 tiles, 2-phase dbuf)
    hipLaunchKernelGGL((gemm_mfma_k<0>), dim3(16, 64), dim3(256), 0, stream,
                       (const __bf16*)ctx16, wot, wo_b, (const float*)nullptr, (const float*)nullptr,
                       out, (__hip_bfloat16*)nullptr, (__hip_bfloat16*)nullptr, (__hip_bfloat16*)nullptr);
}